// Round 8
// baseline (109.237 us; speedup 1.0000x reference)
//
#include <hip/hip_runtime.h>
#include <math.h>

#define T_LEN 8192
#define EPSF  1e-6f

typedef __attribute__((ext_vector_type(8))) short short8;
typedef __attribute__((ext_vector_type(4))) float float4v;

// ---------------------------------------------------------------------------
// R8: OCCUPANCY experiment. 2048 blocks x 256 threads, 128-row strips,
// __launch_bounds__(256,8): 8 blocks/CU = 32 waves/CU (was 16). Theory:
// per-wave latency-bound (additions show 1:1 in dur, removals/rebalances
// neutral across R1-R7); doubling TLP is the one untested axis.
//
// To fit the 64-VGPR/8-wave budget:
//  - B fragments in LDS (R4 fragment-linear layout, proven neutral +
//    bit-correct), read per (h,pt) with laundered index.
//  - MFMA loop h-outer/pt-inner: per-accumulator MFMA sequence UNCHANGED
//    (h0: AhBh,AhBl,AlBh then h1 triple), only one h of A live at a time.
//  - prep re-reads the shapelet from global per pass (3 x 16 dwordx4,
//    L2-hot, same bits, same order) instead of holding S[64] in regs.
//
// Phase 0/1 (one barrier): tid 0-63: serial two-pass znorm + bf16 hi/lo
//   split (bit-identical arithmetic) -> LDS BfragH/L + lsum/ls2.
//   tid 64-111: stage x window (48 float4 -> xs[192] = x[t0-32..t0+159]).
// Phase 1.5: tid<128: window stats row tid (verbatim math), float4 pack
//   {mu,inv,w2} -> lstat. sm4/sv4 -> regs. barrier.
// Phase 2: two 64-row units; per h: pair-packed A from xs (v_perm_b32,
//   bit-identical); per pt: 2 laundered b128 B reads + 3 MFMA; epilogue
//   folds window znorm + exp, float4 stores. t<32 / t>8160 zero-padded.
// LDS: Bfrag 16K + xs 768B + lstat 2K + lsum/ls2 512B = 19.7 KB (x8 = 158K).
// ---------------------------------------------------------------------------
__global__ __launch_bounds__(256, 8) void shapelet_fused(
        const float* __restrict__ x,
        const float* __restrict__ sh,
        float* __restrict__ out) {
    __shared__ short8 BfragH[8][64];           // 8 KB [pt*2+h][lane] hi frags
    __shared__ short8 BfragL[8][64];           // 8 KB lo frags
    __shared__ __align__(16) float xs[192];    // x[t0-32 .. t0+159]
    __shared__ float4 lstat[128];              // {mu, inv, w2, -} per row
    __shared__ __align__(16) float lsum[64];   // logical-p order
    __shared__ __align__(16) float ls2[64];

    const int tid  = threadIdx.x;
    const int lane = tid & 63;
    const int wave = tid >> 6;
    const int n    = lane & 15;
    const int quad = lane >> 4;

    const int super = blockIdx.x & 63;         // 64 strips of 128 rows
    const int b     = blockIdx.x >> 6;         // 32 batches
    const int t0    = super << 7;

    // ---------------- phase 0/1: prep + xs staging ----------
    if (tid < 64) {
        const int p = tid;
        const int pt_p = p & 3;
        const int n_p  = p >> 2;
        const float4* s4 = (const float4*)(sh + (size_t)p * 64);

        // pass 1: sum (S[0]+S[1]+...+S[63], same order as baseline)
        float s1 = 0.f;
#pragma unroll
        for (int i = 0; i < 16; ++i) {
            float4 v = s4[i];
            s1 += v.x; s1 += v.y; s1 += v.z; s1 += v.w;
        }
        float mu = s1 * (1.f / 64.f);

        // pass 2: sq (same order)
        float sq = 0.f;
#pragma unroll
        for (int i = 0; i < 16; ++i) {
            float4 v = s4[i];
            float d0 = v.x - mu; sq = fmaf(d0, d0, sq);
            float d1 = v.y - mu; sq = fmaf(d1, d1, sq);
            float d2 = v.z - mu; sq = fmaf(d2, d2, sq);
            float d3 = v.w - mu; sq = fmaf(d3, d3, sq);
        }
        float sd  = fmaxf(sqrtf(sq * (1.f / 64.f)), EPSF);
        float inv = 1.f / sd;

        // pass 3: pack (two l2 iterations per float4; element order preserved)
        float ssum = 0.f, ss2 = 0.f;
        unsigned* BH = (unsigned*)BfragH;
        unsigned* BL = (unsigned*)BfragL;
#pragma unroll
        for (int i = 0; i < 16; ++i) {
            float4 v4 = s4[i];
            const float el[4] = { v4.x, v4.y, v4.z, v4.w };
#pragma unroll
            for (int half = 0; half < 2; ++half) {
                const int k = 4 * i + 2 * half;     // element index (even)
                unsigned pk_h, pk_l;
                {   // element k (low half)
                    float v = el[2 * half];
                    float s = (v - mu) * inv;
                    unsigned ub = __float_as_uint(s);
                    float hi = __uint_as_float(ub & 0xFFFF0000u);
                    float lo = s - hi;
                    unsigned lb = __float_as_uint(lo) & 0xFFFF0000u;
                    pk_h = ub >> 16;
                    pk_l = lb >> 16;
                    float eff = hi + __uint_as_float(lb);
                    ssum += eff;
                    ss2  = fmaf(eff, eff, ss2);
                }
                {   // element k+1 (high half)
                    float v = el[2 * half + 1];
                    float s = (v - mu) * inv;
                    unsigned ub = __float_as_uint(s);
                    float hi = __uint_as_float(ub & 0xFFFF0000u);
                    float lo = s - hi;
                    unsigned lb = __float_as_uint(lo) & 0xFFFF0000u;
                    pk_h |= (ub & 0xFFFF0000u);
                    pk_l |= lb;
                    float eff = hi + __uint_as_float(lb);
                    ssum += eff;
                    ss2  = fmaf(eff, eff, ss2);
                }
                // fragment-linear address (R4, proven): frag f = pt*2+(k>>5),
                // lane = ((k>>3)&3)*16 + n_p, dword j = (k&7)>>1
                const int f  = (pt_p << 1) + (k >> 5);
                const int li = (((k >> 3) & 3) << 4) + n_p;
                const int di = (((f << 6) + li) << 2) + ((k & 7) >> 1);
                BH[di] = pk_h;
                BL[di] = pk_l;
            }
        }
        lsum[p] = ssum;
        ls2[p]  = ss2;
    } else if (tid < 112) {
        // stage x window into LDS (48 float4 = 192 floats)
        const int i = tid - 64;
        int g0 = t0 - 32 + (i << 2);
        float4 v;
        if (g0 >= 0 && g0 + 3 < T_LEN) {
            v = *(const float4*)(x + (size_t)b * T_LEN + g0);
        } else {
            float* vp = (float*)&v;
#pragma unroll
            for (int e = 0; e < 4; ++e) {
                int g = g0 + e;
                vp[e] = ((unsigned)g < (unsigned)T_LEN) ? x[(size_t)b * T_LEN + g] : 0.f;
            }
        }
        *(float4*)&xs[i << 2] = v;
    }
    __syncthreads();

    // ---------------- phase 1.5: window stats (rows 0..127) ----------------
    if (tid < 128) {
        const int r = tid;
        float s1 = 0.f, sq = 0.f;
#pragma unroll
        for (int l = 0; l < 64; ++l) {
            float v = xs[r + l];
            s1 += v; sq = fmaf(v, v, sq);
        }
        float mu  = s1 * (1.f / 64.f);
        float var = fmaxf(sq * (1.f / 64.f) - mu * mu, 0.f);
        float sd  = fmaxf(sqrtf(var), EPSF);
        float inv = 1.f / sd;
        float4 st;
        st.x = mu;
        st.y = inv;
        st.z = 64.f * var * inv * inv;
        st.w = 0.f;
        lstat[r] = st;
    }
    const float4 sm4 = *(const float4*)&lsum[n << 2];   // logical 4n..4n+3
    const float4 sv4 = *(const float4*)&ls2[n << 2];
    __syncthreads();

    // ---------------- phase 2: MFMA main (2 units, h-outer) ----------------
    const short8* BH8 = (const short8*)BfragH;
    const short8* BL8 = (const short8*)BfragL;

#pragma unroll
    for (int u = 0; u < 2; ++u) {
        const int abase = (u << 6) + (wave << 4) + n + (quad << 3);

        float4v acc[4] = { {0.f,0.f,0.f,0.f}, {0.f,0.f,0.f,0.f},
                           {0.f,0.f,0.f,0.f}, {0.f,0.f,0.f,0.f} };
#pragma unroll
        for (int h = 0; h < 2; ++h) {
            // A fragment for this h: pair-packed (bit-identical element math)
            union { unsigned w[4]; short8 v; } ph, pl;
#pragma unroll
            for (int j2 = 0; j2 < 4; ++j2) {
                float v0 = xs[abase + h * 32 + 2 * j2];
                float v1 = xs[abase + h * 32 + 2 * j2 + 1];
                unsigned u0 = __float_as_uint(v0);
                unsigned u1 = __float_as_uint(v1);
                float l0 = v0 - __uint_as_float(u0 & 0xFFFF0000u);
                float l1 = v1 - __uint_as_float(u1 & 0xFFFF0000u);
                ph.w[j2] = __builtin_amdgcn_perm(u1, u0, 0x07060302u);
                pl.w[j2] = __builtin_amdgcn_perm(__float_as_uint(l1),
                                                 __float_as_uint(l0), 0x07060302u);
            }
            const short8 Ah = ph.v;
            const short8 Al = pl.v;

#pragma unroll
            for (int pt = 0; pt < 4; ++pt) {
                // per-use B reads (laundered; fragment f = pt*2 + h)
                unsigned off = ((unsigned)(((pt << 1) + h)) << 6) + (unsigned)lane;
                asm volatile("" : "+v"(off));
                short8 bh = BH8[off];
                short8 bl = BL8[off];
                // per-acc order identical to baseline: h0 triple then h1 triple
                float4v a = acc[pt];
                a = __builtin_amdgcn_mfma_f32_16x16x32_bf16(Ah, bh, a, 0, 0, 0);
                a = __builtin_amdgcn_mfma_f32_16x16x32_bf16(Ah, bl, a, 0, 0, 0);
                a = __builtin_amdgcn_mfma_f32_16x16x32_bf16(Al, bh, a, 0, 0, 0);
                acc[pt] = a;
            }
        }

        // epilogue: fold window znorm + exp, float4 store at cols 4n..4n+3
#pragma unroll
        for (int r = 0; r < 4; ++r) {
            // C/D layout: col = lane&15, row = quad*4 + r
            int tl = (u << 6) + (wave << 4) + (quad << 2) + r;
            int tg = t0 + tl;
            bool valid = (tg >= 32) && (tg <= 8160);
            float4 st = lstat[tl];
            float mu  = st.x;
            float inv = st.y;
            float w2  = st.z;
            float d0 = (acc[0][r] - mu * sm4.x) * inv;
            float d1 = (acc[1][r] - mu * sm4.y) * inv;
            float d2 = (acc[2][r] - mu * sm4.z) * inv;
            float d3 = (acc[3][r] - mu * sm4.w) * inv;
            float4 o;
            o.x = valid ? __expf(-(w2 + sv4.x - 2.f * d0)) : 0.f;
            o.y = valid ? __expf(-(w2 + sv4.y - 2.f * d1)) : 0.f;
            o.z = valid ? __expf(-(w2 + sv4.z - 2.f * d2)) : 0.f;
            o.w = valid ? __expf(-(w2 + sv4.w - 2.f * d3)) : 0.f;
            *(float4*)(out + (((size_t)(b * T_LEN + tg)) << 6) + (n << 2)) = o;
        }
    }
}

extern "C" void kernel_launch(void* const* d_in, const int* in_sizes, int n_in,
                              void* d_out, int out_size, void* d_ws, size_t ws_size,
                              hipStream_t stream) {
    const float* x  = (const float*)d_in[0];   // (32, 8192, 1)
    const float* sh = (const float*)d_in[1];   // (64, 1, 64)
    float* out = (float*)d_out;                // (32, 8192, 64)

    shapelet_fused<<<32 * 64, 256, 0, stream>>>(x, sh, out);
}